// Round 7
// baseline (1388.370 us; speedup 1.0000x reference)
//
#include <hip/hip_runtime.h>

#define Bc 8
#define Tc 4096
#define Dc 768
#define Hc 12
#define HDc 64
#define Kc 32
#define TD3 2304
#define WQKV_F (TD3 * Dc)          // 1,769,472 floats
#define WALL_F ((TD3 + Dc) * Dc)   // 2,359,296 floats (wqkv + wout)
#define XS_F (Bc * Kc * Dc)        //   196,608 floats
#define NBLK 1024

typedef __attribute__((ext_vector_type(8))) short short8;
typedef __attribute__((ext_vector_type(4))) short short4v;
typedef __attribute__((ext_vector_type(4))) float float4v;

__device__ __forceinline__ float bf2f(unsigned short u) {
    unsigned v = ((unsigned)u) << 16;
    return __builtin_bit_cast(float, v);
}
__device__ __forceinline__ unsigned short f2bf(float f) {
    unsigned u = __builtin_bit_cast(unsigned, f);
    u += 0x7FFFu + ((u >> 16) & 1u);   // RNE
    return (unsigned short)(u >> 16);
}
__device__ __forceinline__ void split8(const float* p, short8& hi, short8& lo) {
#pragma unroll
    for (int i = 0; i < 8; ++i) {
        unsigned short h = f2bf(p[i]);
        hi[i] = (short)h;
        lo[i] = (short)f2bf(p[i] - bf2f(h));
    }
}
__device__ __forceinline__ void split4(const float4v v, short4v& h, short4v& l) {
#pragma unroll
    for (int q = 0; q < 4; ++q) {
        unsigned short hb = f2bf(v[q]);
        h[q] = (short)hb;
        l[q] = (short)f2bf(v[q] - bf2f(hb));
    }
}

// ---------------------------------------------------------------------------
// Device-scope grid barrier (sense-reversing, single slot pair reused).
// AGENT-scope acq_rel atomics provide the cross-XCD L2 writeback/invalidate
// (same mechanism cooperative grid.sync uses). All NBLK blocks are co-resident
// by construction (4 blocks/CU x 256 CUs). Spin has a ~200ms bailout so a
// failure is a visible wrong-answer, not a hung container.
// ---------------------------------------------------------------------------
__device__ __forceinline__ void gbar(unsigned* cnt, unsigned* gen) {
    __syncthreads();
    if (threadIdx.x == 0) {
        unsigned g = __hip_atomic_load(gen, __ATOMIC_RELAXED, __HIP_MEMORY_SCOPE_AGENT);
        unsigned a = __hip_atomic_fetch_add(cnt, 1u, __ATOMIC_ACQ_REL, __HIP_MEMORY_SCOPE_AGENT) + 1;
        if (a == (unsigned)NBLK) {
            __hip_atomic_store(cnt, 0u, __ATOMIC_RELAXED, __HIP_MEMORY_SCOPE_AGENT);
            __hip_atomic_fetch_add(gen, 1u, __ATOMIC_RELEASE, __HIP_MEMORY_SCOPE_AGENT);
        } else {
            int it = 0;
            while (__hip_atomic_load(gen, __ATOMIC_ACQUIRE, __HIP_MEMORY_SCOPE_AGENT) == g) {
                __builtin_amdgcn_s_sleep(2);
                if (++it > 4000000) break;   // bail out, fail visibly
            }
        }
    }
    __syncthreads();
}

// ---------------------------------------------------------------------------
// Mega kernel: all 6 phases (R5-validated bodies), 5 grid barriers.
// Grid 1024 x 256, 4 blocks/CU guaranteed (LDS 28.25KB, VGPR capped by bounds).
// ---------------------------------------------------------------------------
__global__ __launch_bounds__(256, 4) void mega(
        const float* __restrict__ x, const float* __restrict__ sb,
        const float* __restrict__ wqkv, const float* __restrict__ wout,
        const float* __restrict__ sfilt, float* __restrict__ out,
        float* __restrict__ pb, short* __restrict__ w_hi, short* __restrict__ w_lo,
        short* __restrict__ xs_hi, short* __restrict__ xs_lo,
        float* __restrict__ c1, float* __restrict__ fhn, float* __restrict__ proj,
        unsigned* __restrict__ bar) {
    __shared__ float smem[32 * 193 + 32 * 33];   // k1: xt+st; k5: pt (aliased)
    float* xt = smem;
    float* st = smem + 32 * 193;

    int tid = threadIdx.x;
    int bid = blockIdx.x;
    int w    = tid >> 6;
    int lane = tid & 63;
    int col  = lane & 15;
    int quad = lane >> 4;
    unsigned* cnt = bar;
    unsigned* gen = bar + 16;        // separate cachelines
    const short* wo_hi = w_hi + (size_t)WQKV_F;
    const short* wo_lo = w_lo + (size_t)WQKV_F;

    // ---- P0: k1 spectral GEMM (jobs 0..511) + weight conversion (512..2815)
    for (int j = bid; j < 2816; j += NBLK) {
        if (j >= 512) {
            int i = ((j - 512) * 256 + tid) * 4;
            const float* src = (i < WQKV_F) ? (wqkv + i) : (wout + (i - WQKV_F));
            float4v v = *(const float4v*)src;
            short4v h, l;
            split4(v, h, l);
            *(short4v*)(w_hi + i) = h;
            *(short4v*)(w_lo + i) = l;
            continue;
        }
        int b  = j >> 6;
        int dt = (j >> 4) & 3;
        int tc = j & 15;
        int d0 = dt * 192;
        size_t bT = (size_t)b * Tc + (size_t)tc * 256;

        float4v acc[2][3];
#pragma unroll
        for (int mi = 0; mi < 2; ++mi)
#pragma unroll
            for (int ni = 0; ni < 3; ++ni) acc[mi][ni] = (float4v){0.f, 0.f, 0.f, 0.f};

        for (int ks = 0; ks < 8; ++ks) {
            __syncthreads();
#pragma unroll
            for (int i = 0; i < 6; ++i) {
                int f4  = tid + i * 256;
                int row = f4 / 48, c4 = f4 % 48;
                float4v v = *(const float4v*)&x[(bT + ks * 32 + row) * Dc + d0 + c4 * 4];
#pragma unroll
                for (int q = 0; q < 4; ++q) xt[row * 193 + c4 * 4 + q] = v[q];
            }
            {
                int row = tid >> 3, c4 = tid & 7;
                float4v v = *(const float4v*)&sb[(bT + ks * 32 + row) * Kc + c4 * 4];
#pragma unroll
                for (int q = 0; q < 4; ++q) st[row * 33 + c4 * 4 + q] = v[q];
            }
            __syncthreads();

            short8 ah[2], al[2];
#pragma unroll
            for (int mi = 0; mi < 2; ++mi) {
                float av[8];
#pragma unroll
                for (int jj = 0; jj < 8; ++jj)
                    av[jj] = st[(quad * 8 + jj) * 33 + mi * 16 + col];
                split8(av, ah[mi], al[mi]);
            }
#pragma unroll
            for (int ni = 0; ni < 3; ++ni) {
                int nc = (w * 3 + ni) * 16 + col;
                float bv[8];
#pragma unroll
                for (int jj = 0; jj < 8; ++jj)
                    bv[jj] = xt[(quad * 8 + jj) * 193 + nc];
                short8 bh, bl;
                split8(bv, bh, bl);
#pragma unroll
                for (int mi = 0; mi < 2; ++mi) {
                    acc[mi][ni] = __builtin_amdgcn_mfma_f32_16x16x32_bf16(ah[mi], bh, acc[mi][ni], 0, 0, 0);
                    acc[mi][ni] = __builtin_amdgcn_mfma_f32_16x16x32_bf16(al[mi], bh, acc[mi][ni], 0, 0, 0);
                    acc[mi][ni] = __builtin_amdgcn_mfma_f32_16x16x32_bf16(ah[mi], bl, acc[mi][ni], 0, 0, 0);
                }
            }
        }

        float* pbp = pb + (size_t)tc * XS_F;
#pragma unroll
        for (int mi = 0; mi < 2; ++mi)
#pragma unroll
            for (int ni = 0; ni < 3; ++ni)
#pragma unroll
                for (int r = 0; r < 4; ++r) {
                    int kk = mi * 16 + quad * 4 + r;
                    int dd = d0 + (w * 3 + ni) * 16 + col;
                    pbp[((size_t)(b * Kc + kk)) * Dc + dd] = acc[mi][ni][r];
                }
    }
    gbar(cnt, gen);

    // ---- P1: reduce 16 partials -> xs bf16 planes (R5 k1r)
    {
        int idx = bid * 256 + tid;
        if (idx < 49152) {
            int i = idx * 4;
            float4v s = (float4v){0.f, 0.f, 0.f, 0.f};
#pragma unroll
            for (int p = 0; p < 16; ++p) {
                float4v v = *(const float4v*)(pb + (size_t)p * XS_F + i);
#pragma unroll
                for (int q = 0; q < 4; ++q) s[q] += v[q];
            }
            short4v h, l;
            split4(s, h, l);
            *(short4v*)(xs_hi + i) = h;
            *(short4v*)(xs_lo + i) = l;
        }
    }
    gbar(cnt, gen);

    // ---- P2: qkv GEMM (R5 k2, 288 block-jobs)
    if (bid < 288) {
        int m = col, mb = bid & 7, nb = bid >> 3;
        int m0 = mb * 32;
        int n0 = nb * 64 + w * 16;

        const short* a0h = xs_hi + (size_t)(m0 + m) * Dc + quad * 8;
        const short* a0l = xs_lo + (size_t)(m0 + m) * Dc + quad * 8;
        const short* a1h = a0h + (size_t)16 * Dc;
        const short* a1l = a0l + (size_t)16 * Dc;
        const short* bhp = w_hi + (size_t)(n0 + m) * Dc + quad * 8;
        const short* blp = w_lo + (size_t)(n0 + m) * Dc + quad * 8;

        float4v acc0 = (float4v){0.f, 0.f, 0.f, 0.f};
        float4v acc1 = (float4v){0.f, 0.f, 0.f, 0.f};
#pragma unroll 4
        for (int s = 0; s < 24; ++s) {
            short8 bh = *(const short8*)(bhp + s * 32);
            short8 bl = *(const short8*)(blp + s * 32);
            short8 h0 = *(const short8*)(a0h + s * 32);
            short8 l0 = *(const short8*)(a0l + s * 32);
            short8 h1 = *(const short8*)(a1h + s * 32);
            short8 l1 = *(const short8*)(a1l + s * 32);
            acc0 = __builtin_amdgcn_mfma_f32_16x16x32_bf16(h0, bh, acc0, 0, 0, 0);
            acc0 = __builtin_amdgcn_mfma_f32_16x16x32_bf16(l0, bh, acc0, 0, 0, 0);
            acc0 = __builtin_amdgcn_mfma_f32_16x16x32_bf16(h0, bl, acc0, 0, 0, 0);
            acc1 = __builtin_amdgcn_mfma_f32_16x16x32_bf16(h1, bh, acc1, 0, 0, 0);
            acc1 = __builtin_amdgcn_mfma_f32_16x16x32_bf16(l1, bh, acc1, 0, 0, 0);
            acc1 = __builtin_amdgcn_mfma_f32_16x16x32_bf16(h1, bl, acc1, 0, 0, 0);
        }
        float* cp0 = c1 + (size_t)(m0 + quad * 4) * TD3 + n0 + m;
        float* cp1 = cp0 + (size_t)16 * TD3;
#pragma unroll
        for (int r = 0; r < 4; ++r) {
            cp0[(size_t)r * TD3] = acc0[r];
            cp1[(size_t)r * TD3] = acc1[r];
        }
    }
    gbar(cnt, gen);

    // ---- P3: FHN (R5 k3, 3072 scalar jobs)
    {
        int idx = bid * 256 + tid;
        if (idx < Bc * Hc * Kc) {
            int kk = idx & 31;
            int bh = idx >> 5;
            int h  = bh % Hc;
            int r  = (bh / Hc) * Kc + kk;

            const float* qp = c1 + (size_t)r * TD3 + h * HDc;
            const float* kp = qp + Dc;
            float s = 0.f;
#pragma unroll
            for (int dd = 0; dd < HDc; ++dd) s = fmaf(qp[dd], kp[dd], s);
            s *= 0.125f;

            float filt = 1.f / (1.f + __expf(-sfilt[h * 32 + kk]));
            s *= filt;

            float as    = fabsf(s);
            float scale = fmaxf(as, 1e-6f);
            float sn    = s / scale;
            float gate  = 1.f / (1.f + __expf(-(as - 0.5f) * 10.f));
            float I     = sn * (0.1f + 0.9f * gate);
            const float alpha = 0.08f;
            const float denom = 1.064f;
            float v = 0.f, ww = 0.f;
#pragma unroll
            for (int it = 0; it < 2; ++it) {
                float dv = v - (v * v * v) / 3.f - ww + I;
                float vn = v + dv;
                float wn = (ww + (vn + 0.7f) * alpha) / denom;
                v = fminf(fmaxf(vn, -3.f), 3.f);
                ww = fminf(fmaxf(wn, -3.f), 3.f);
            }
            fhn[idx] = v * scale;
        }
    }
    gbar(cnt, gen);

    // ---- P4: proj GEMM (R5 k4, 192 block-jobs / 768 waves)
    if (bid < 192) {
        int wave = bid * 4 + w;
        int m = col;
        int mb = wave & 15;
        int nt = wave >> 4;
        int m0 = mb * 16, n0 = nt * 16;

        const short* bhp = wo_hi + (size_t)(n0 + m) * Dc + quad * 8;
        const short* blp = wo_lo + (size_t)(n0 + m) * Dc + quad * 8;

        int r = m0 + m;
        int b = r >> 5, kk = r & 31;
        const float* apx = c1 + (size_t)r * TD3 + 2 * Dc + quad * 8;
        const float* fp  = fhn + (size_t)b * Hc * Kc + kk;

        float4v acc = (float4v){0.f, 0.f, 0.f, 0.f};
#pragma unroll 4
        for (int s = 0; s < 24; ++s) {
            int h = (s * 32 + quad * 8) >> 6;
            float f = fp[h * Kc];
            float av[8];
#pragma unroll
            for (int i = 0; i < 8; ++i) av[i] = apx[s * 32 + i] * f;
            short8 ah, al;
            split8(av, ah, al);
            short8 bh = *(const short8*)(bhp + s * 32);
            short8 bl = *(const short8*)(blp + s * 32);
            acc = __builtin_amdgcn_mfma_f32_16x16x32_bf16(ah, bh, acc, 0, 0, 0);
            acc = __builtin_amdgcn_mfma_f32_16x16x32_bf16(al, bh, acc, 0, 0, 0);
            acc = __builtin_amdgcn_mfma_f32_16x16x32_bf16(ah, bl, acc, 0, 0, 0);
        }
        float* cp = proj + (size_t)(m0 + quad * 4) * Dc + n0 + m;
#pragma unroll
        for (int rr = 0; rr < 4; ++rr) cp[(size_t)rr * Dc] = acc[rr];
    }
    gbar(cnt, gen);

    // ---- P5: out GEMM (R5 k5, 2048 jobs, 2 per block; pt aliases smem)
    for (int j = bid; j < 2048; j += NBLK) {
        __syncthreads();               // guard smem reuse between jobs
        float* pt = smem;

        int b  = j >> 8;
        int tt = (j >> 2) & 63;
        int et = j & 3;
        int t0 = tt * 64 + w * 16;
        int e0 = et * 192;

#pragma unroll
        for (int i = 0; i < 6; ++i) {
            int f4  = tid + i * 256;
            int row = f4 / 48, c4 = f4 % 48;
            float4v v = *(const float4v*)&proj[(size_t)b * Kc * Dc + (size_t)row * Dc + e0 + c4 * 4];
#pragma unroll
            for (int q = 0; q < 4; ++q) pt[row * 193 + c4 * 4 + q] = v[q];
        }

        const float* apx = sb + ((size_t)b * Tc + t0 + col) * Kc + quad * 8;
        short8 ah, al;
        split8(apx, ah, al);

        __syncthreads();

        float4v acc[12];
#pragma unroll
        for (int ni = 0; ni < 12; ++ni) acc[ni] = (float4v){0.f, 0.f, 0.f, 0.f};

#pragma unroll
        for (int ni = 0; ni < 12; ++ni) {
            float bv[8];
#pragma unroll
            for (int jj = 0; jj < 8; ++jj)
                bv[jj] = pt[(quad * 8 + jj) * 193 + ni * 16 + col];
            short8 bh, bl;
            split8(bv, bh, bl);
            acc[ni] = __builtin_amdgcn_mfma_f32_16x16x32_bf16(ah, bh, acc[ni], 0, 0, 0);
            acc[ni] = __builtin_amdgcn_mfma_f32_16x16x32_bf16(al, bh, acc[ni], 0, 0, 0);
            acc[ni] = __builtin_amdgcn_mfma_f32_16x16x32_bf16(ah, bl, acc[ni], 0, 0, 0);
        }

        float* op = out + ((size_t)b * Tc + t0 + quad * 4) * Dc + e0 + col;
#pragma unroll
        for (int ni = 0; ni < 12; ++ni)
#pragma unroll
            for (int r = 0; r < 4; ++r)
                op[(size_t)r * Dc + ni * 16] = acc[ni][r];
    }
}

extern "C" void kernel_launch(void* const* d_in, const int* in_sizes, int n_in,
                              void* d_out, int out_size, void* d_ws, size_t ws_size,
                              hipStream_t stream) {
    const float* x     = (const float*)d_in[0];
    const float* sb    = (const float*)d_in[1];
    const float* wqkv  = (const float*)d_in[2];
    const float* wout  = (const float*)d_in[3];
    const float* sfilt = (const float*)d_in[4];
    float* out = (float*)d_out;

    // workspace layout (~26.8 MB + barrier page)
    float* pb    = (float*)d_ws;                        // 16*XS_F f (12.6 MB)
    short* w_hi  = (short*)(pb + (size_t)16 * XS_F);    // WALL_F sh
    short* w_lo  = w_hi + (size_t)WALL_F;               // WALL_F sh
    short* xs_hi = w_lo + (size_t)WALL_F;               // XS_F sh
    short* xs_lo = xs_hi + (size_t)XS_F;                // XS_F sh
    float* c1    = (float*)(xs_lo + (size_t)XS_F);      // 589,824 f
    float* fhn   = c1 + (size_t)Bc * Kc * TD3;          // 3,072 f
    float* proj  = fhn + (size_t)Bc * Hc * Kc;          // XS_F f
    unsigned* bar = (unsigned*)((char*)d_ws + (size_t)28 * 1024 * 1024);

    hipMemsetAsync(bar, 0, 128, stream);                // zero barrier slots (capturable)
    hipLaunchKernelGGL(mega, dim3(NBLK), dim3(256), 0, stream,
                       x, sb, wqkv, wout, sfilt, out,
                       pb, w_hi, w_lo, xs_hi, xs_lo, c1, fhn, proj, bar);
}

// Round 8
// 846.599 us; speedup vs baseline: 1.6399x; 1.6399x over previous
//
#include <hip/hip_runtime.h>

#define Bc 8
#define Tc 4096
#define Dc 768
#define Hc 12
#define HDc 64
#define Kc 32
#define TD3 2304
#define WQKV_F (TD3 * Dc)          // 1,769,472 floats
#define WALL_F ((TD3 + Dc) * Dc)   // 2,359,296 floats (wqkv + wout)
#define XS_F (Bc * Kc * Dc)        //   196,608 floats
#define NBLK 768                   // 3 blocks/CU x 256 CUs, co-resident by construction
#define BAR_STRIDE 4096            // uints per barrier slot (16 KB)

typedef __attribute__((ext_vector_type(8))) short short8;
typedef __attribute__((ext_vector_type(4))) short short4v;
typedef __attribute__((ext_vector_type(4))) float float4v;

__device__ __forceinline__ float bf2f(unsigned short u) {
    unsigned v = ((unsigned)u) << 16;
    return __builtin_bit_cast(float, v);
}
__device__ __forceinline__ unsigned short f2bf(float f) {
    unsigned u = __builtin_bit_cast(unsigned, f);
    u += 0x7FFFu + ((u >> 16) & 1u);   // RNE
    return (unsigned short)(u >> 16);
}
__device__ __forceinline__ void split8(const float* p, short8& hi, short8& lo) {
#pragma unroll
    for (int i = 0; i < 8; ++i) {
        unsigned short h = f2bf(p[i]);
        hi[i] = (short)h;
        lo[i] = (short)f2bf(p[i] - bf2f(h));
    }
}
__device__ __forceinline__ void split4(const float4v v, short4v& h, short4v& l) {
#pragma unroll
    for (int q = 0; q < 4; ++q) {
        unsigned short hb = f2bf(v[q]);
        h[q] = (short)hb;
        l[q] = (short)f2bf(v[q] - bf2f(hb));
    }
}

// ---------------------------------------------------------------------------
// Hierarchical device-scope grid barrier. R7's flat version was correct but
// cost ~240us/barrier: 1024 ACQ_REL RMWs on ONE cacheline (cross-XCD bounce,
// ~560cyc/op serialized) + un-throttled acquire-poll invalidate storm.
// Fix: 64 leaf lines (12 arrivals each, parallel) -> 8 mids (8 each) ->
// root (8); max same-line chain = 12. Spin throttled with s_sleep(32).
// Per-barrier slot set (memset-zeroed) -> no reset logic, no reuse races.
// Release chain: each level's ACQ_REL RMW acquires the level below, so the
// final releaser's gen store RELEASE publishes all phase writes; spinners
// ACQUIRE gen. Bailout makes a wedged barrier a visible FAIL, not a hang.
// ---------------------------------------------------------------------------
__device__ __forceinline__ void gbar(unsigned* base) {
    __syncthreads();
    if (threadIdx.x == 0) {
        int lf = blockIdx.x & 63;
        unsigned* leaf = base + lf * 32;
        unsigned* mid  = base + 2048 + (lf >> 3) * 32;
        unsigned* root = base + 2304;
        unsigned* gen  = base + 2336;
        bool released = false;
        unsigned l = __hip_atomic_fetch_add(leaf, 1u, __ATOMIC_ACQ_REL, __HIP_MEMORY_SCOPE_AGENT);
        if (l == (NBLK / 64) - 1) {                       // last of 12 on this leaf
            unsigned m = __hip_atomic_fetch_add(mid, 1u, __ATOMIC_ACQ_REL, __HIP_MEMORY_SCOPE_AGENT);
            if (m == 7) {                                 // last of 8 leaves on this mid
                unsigned r = __hip_atomic_fetch_add(root, 1u, __ATOMIC_ACQ_REL, __HIP_MEMORY_SCOPE_AGENT);
                if (r == 7) {                             // last of 8 mids
                    __hip_atomic_store(gen, 1u, __ATOMIC_RELEASE, __HIP_MEMORY_SCOPE_AGENT);
                    released = true;
                }
            }
        }
        if (!released) {
            int it = 0;
            while (__hip_atomic_load(gen, __ATOMIC_ACQUIRE, __HIP_MEMORY_SCOPE_AGENT) == 0u) {
                __builtin_amdgcn_s_sleep(32);             // ~2k cyc between polls
                if (++it > 300000) break;                 // ~0.5s bailout, fail visibly
            }
        }
    }
    __syncthreads();
}

// ---------------------------------------------------------------------------
// Mega kernel v2: all 6 phases (R5/R7-validated bodies), 5 hierarchical
// barriers. Grid 768 x 256, __launch_bounds__(256,3): 3 blocks/CU guaranteed
// (LDS 28.9KB x3 = 87KB <= 160KB), VGPR cap ~160 (kills R7's 64-VGPR spills).
// ---------------------------------------------------------------------------
__global__ __launch_bounds__(256, 3) void mega(
        const float* __restrict__ x, const float* __restrict__ sb,
        const float* __restrict__ wqkv, const float* __restrict__ wout,
        const float* __restrict__ sfilt, float* __restrict__ out,
        float* __restrict__ pb, short* __restrict__ w_hi, short* __restrict__ w_lo,
        short* __restrict__ xs_hi, short* __restrict__ xs_lo,
        float* __restrict__ c1, float* __restrict__ fhn, float* __restrict__ proj,
        unsigned* __restrict__ bar) {
    __shared__ float smem[32 * 193 + 32 * 33];   // k1: xt+st; k5: pt (aliased)
    float* xt = smem;
    float* st = smem + 32 * 193;

    int tid = threadIdx.x;
    int bid = blockIdx.x;
    int w    = tid >> 6;
    int lane = tid & 63;
    int col  = lane & 15;
    int quad = lane >> 4;
    const short* wo_hi = w_hi + (size_t)WQKV_F;
    const short* wo_lo = w_lo + (size_t)WQKV_F;

    // ---- P0: k1 spectral GEMM (blocks 0..511) || weight conversion (512..767)
    if (bid >= 512) {
        for (int c = bid - 512; c < 2304; c += 256) {   // 9 conv jobs/block
            int i = (c * 256 + tid) * 4;
            const float* src = (i < WQKV_F) ? (wqkv + i) : (wout + (i - WQKV_F));
            float4v v = *(const float4v*)src;
            short4v h, l;
            split4(v, h, l);
            *(short4v*)(w_hi + i) = h;
            *(short4v*)(w_lo + i) = l;
        }
    } else {
        int b  = bid >> 6;
        int dt = (bid >> 4) & 3;
        int tc = bid & 15;
        int d0 = dt * 192;
        size_t bT = (size_t)b * Tc + (size_t)tc * 256;

        float4v acc[2][3];
#pragma unroll
        for (int mi = 0; mi < 2; ++mi)
#pragma unroll
            for (int ni = 0; ni < 3; ++ni) acc[mi][ni] = (float4v){0.f, 0.f, 0.f, 0.f};

        for (int ks = 0; ks < 8; ++ks) {
            __syncthreads();
#pragma unroll
            for (int i = 0; i < 6; ++i) {
                int f4  = tid + i * 256;
                int row = f4 / 48, c4 = f4 % 48;
                float4v v = *(const float4v*)&x[(bT + ks * 32 + row) * Dc + d0 + c4 * 4];
#pragma unroll
                for (int q = 0; q < 4; ++q) xt[row * 193 + c4 * 4 + q] = v[q];
            }
            {
                int row = tid >> 3, c4 = tid & 7;
                float4v v = *(const float4v*)&sb[(bT + ks * 32 + row) * Kc + c4 * 4];
#pragma unroll
                for (int q = 0; q < 4; ++q) st[row * 33 + c4 * 4 + q] = v[q];
            }
            __syncthreads();

            short8 ah[2], al[2];
#pragma unroll
            for (int mi = 0; mi < 2; ++mi) {
                float av[8];
#pragma unroll
                for (int jj = 0; jj < 8; ++jj)
                    av[jj] = st[(quad * 8 + jj) * 33 + mi * 16 + col];
                split8(av, ah[mi], al[mi]);
            }
#pragma unroll
            for (int ni = 0; ni < 3; ++ni) {
                int nc = (w * 3 + ni) * 16 + col;
                float bv[8];
#pragma unroll
                for (int jj = 0; jj < 8; ++jj)
                    bv[jj] = xt[(quad * 8 + jj) * 193 + nc];
                short8 bh, bl;
                split8(bv, bh, bl);
#pragma unroll
                for (int mi = 0; mi < 2; ++mi) {
                    acc[mi][ni] = __builtin_amdgcn_mfma_f32_16x16x32_bf16(ah[mi], bh, acc[mi][ni], 0, 0, 0);
                    acc[mi][ni] = __builtin_amdgcn_mfma_f32_16x16x32_bf16(al[mi], bh, acc[mi][ni], 0, 0, 0);
                    acc[mi][ni] = __builtin_amdgcn_mfma_f32_16x16x32_bf16(ah[mi], bl, acc[mi][ni], 0, 0, 0);
                }
            }
        }

        float* pbp = pb + (size_t)tc * XS_F;
#pragma unroll
        for (int mi = 0; mi < 2; ++mi)
#pragma unroll
            for (int ni = 0; ni < 3; ++ni)
#pragma unroll
                for (int r = 0; r < 4; ++r) {
                    int kk = mi * 16 + quad * 4 + r;
                    int dd = d0 + (w * 3 + ni) * 16 + col;
                    pbp[((size_t)(b * Kc + kk)) * Dc + dd] = acc[mi][ni][r];
                }
    }
    gbar(bar);

    // ---- P1: reduce 16 partials -> xs bf16 planes
    {
        int idx = bid * 256 + tid;
        if (idx < 49152) {
            int i = idx * 4;
            float4v s = (float4v){0.f, 0.f, 0.f, 0.f};
#pragma unroll
            for (int p = 0; p < 16; ++p) {
                float4v v = *(const float4v*)(pb + (size_t)p * XS_F + i);
#pragma unroll
                for (int q = 0; q < 4; ++q) s[q] += v[q];
            }
            short4v h, l;
            split4(s, h, l);
            *(short4v*)(xs_hi + i) = h;
            *(short4v*)(xs_lo + i) = l;
        }
    }
    gbar(bar + BAR_STRIDE);

    // ---- P2: qkv GEMM (288 block-jobs)
    if (bid < 288) {
        int m = col, mb = bid & 7, nb = bid >> 3;
        int m0 = mb * 32;
        int n0 = nb * 64 + w * 16;

        const short* a0h = xs_hi + (size_t)(m0 + m) * Dc + quad * 8;
        const short* a0l = xs_lo + (size_t)(m0 + m) * Dc + quad * 8;
        const short* a1h = a0h + (size_t)16 * Dc;
        const short* a1l = a0l + (size_t)16 * Dc;
        const short* bhp = w_hi + (size_t)(n0 + m) * Dc + quad * 8;
        const short* blp = w_lo + (size_t)(n0 + m) * Dc + quad * 8;

        float4v acc0 = (float4v){0.f, 0.f, 0.f, 0.f};
        float4v acc1 = (float4v){0.f, 0.f, 0.f, 0.f};
#pragma unroll 4
        for (int s = 0; s < 24; ++s) {
            short8 bh = *(const short8*)(bhp + s * 32);
            short8 bl = *(const short8*)(blp + s * 32);
            short8 h0 = *(const short8*)(a0h + s * 32);
            short8 l0 = *(const short8*)(a0l + s * 32);
            short8 h1 = *(const short8*)(a1h + s * 32);
            short8 l1 = *(const short8*)(a1l + s * 32);
            acc0 = __builtin_amdgcn_mfma_f32_16x16x32_bf16(h0, bh, acc0, 0, 0, 0);
            acc0 = __builtin_amdgcn_mfma_f32_16x16x32_bf16(l0, bh, acc0, 0, 0, 0);
            acc0 = __builtin_amdgcn_mfma_f32_16x16x32_bf16(h0, bl, acc0, 0, 0, 0);
            acc1 = __builtin_amdgcn_mfma_f32_16x16x32_bf16(h1, bh, acc1, 0, 0, 0);
            acc1 = __builtin_amdgcn_mfma_f32_16x16x32_bf16(l1, bh, acc1, 0, 0, 0);
            acc1 = __builtin_amdgcn_mfma_f32_16x16x32_bf16(h1, bl, acc1, 0, 0, 0);
        }
        float* cp0 = c1 + (size_t)(m0 + quad * 4) * TD3 + n0 + m;
        float* cp1 = cp0 + (size_t)16 * TD3;
#pragma unroll
        for (int r = 0; r < 4; ++r) {
            cp0[(size_t)r * TD3] = acc0[r];
            cp1[(size_t)r * TD3] = acc1[r];
        }
    }
    gbar(bar + 2 * BAR_STRIDE);

    // ---- P3: FHN (3072 scalar jobs)
    {
        int idx = bid * 256 + tid;
        if (idx < Bc * Hc * Kc) {
            int kk = idx & 31;
            int bh = idx >> 5;
            int h  = bh % Hc;
            int r  = (bh / Hc) * Kc + kk;

            const float* qp = c1 + (size_t)r * TD3 + h * HDc;
            const float* kp = qp + Dc;
            float s = 0.f;
#pragma unroll
            for (int dd = 0; dd < HDc; ++dd) s = fmaf(qp[dd], kp[dd], s);
            s *= 0.125f;

            float filt = 1.f / (1.f + __expf(-sfilt[h * 32 + kk]));
            s *= filt;

            float as    = fabsf(s);
            float scale = fmaxf(as, 1e-6f);
            float sn    = s / scale;
            float gate  = 1.f / (1.f + __expf(-(as - 0.5f) * 10.f));
            float I     = sn * (0.1f + 0.9f * gate);
            const float alpha = 0.08f;
            const float denom = 1.064f;
            float v = 0.f, ww = 0.f;
#pragma unroll
            for (int it = 0; it < 2; ++it) {
                float dv = v - (v * v * v) / 3.f - ww + I;
                float vn = v + dv;
                float wn = (ww + (vn + 0.7f) * alpha) / denom;
                v = fminf(fmaxf(vn, -3.f), 3.f);
                ww = fminf(fmaxf(wn, -3.f), 3.f);
            }
            fhn[idx] = v * scale;
        }
    }
    gbar(bar + 3 * BAR_STRIDE);

    // ---- P4: proj GEMM (192 block-jobs / 768 waves)
    if (bid < 192) {
        int wave = bid * 4 + w;
        int m = col;
        int mb = wave & 15;
        int nt = wave >> 4;
        int m0 = mb * 16, n0 = nt * 16;

        const short* bhp = wo_hi + (size_t)(n0 + m) * Dc + quad * 8;
        const short* blp = wo_lo + (size_t)(n0 + m) * Dc + quad * 8;

        int r = m0 + m;
        int b = r >> 5, kk = r & 31;
        const float* apx = c1 + (size_t)r * TD3 + 2 * Dc + quad * 8;
        const float* fp  = fhn + (size_t)b * Hc * Kc + kk;

        float4v acc = (float4v){0.f, 0.f, 0.f, 0.f};
#pragma unroll 4
        for (int s = 0; s < 24; ++s) {
            int h = (s * 32 + quad * 8) >> 6;
            float f = fp[h * Kc];
            float av[8];
#pragma unroll
            for (int i = 0; i < 8; ++i) av[i] = apx[s * 32 + i] * f;
            short8 ah, al;
            split8(av, ah, al);
            short8 bh = *(const short8*)(bhp + s * 32);
            short8 bl = *(const short8*)(blp + s * 32);
            acc = __builtin_amdgcn_mfma_f32_16x16x32_bf16(ah, bh, acc, 0, 0, 0);
            acc = __builtin_amdgcn_mfma_f32_16x16x32_bf16(al, bh, acc, 0, 0, 0);
            acc = __builtin_amdgcn_mfma_f32_16x16x32_bf16(ah, bl, acc, 0, 0, 0);
        }
        float* cp = proj + (size_t)(m0 + quad * 4) * Dc + n0 + m;
#pragma unroll
        for (int rr = 0; rr < 4; ++rr) cp[(size_t)rr * Dc] = acc[rr];
    }
    gbar(bar + 4 * BAR_STRIDE);

    // ---- P5: out GEMM (2048 jobs, grid-stride; pt aliases smem)
    for (int j = bid; j < 2048; j += NBLK) {
        __syncthreads();               // guard smem reuse between jobs
        float* pt = smem;

        int b  = j >> 8;
        int tt = (j >> 2) & 63;
        int et = j & 3;
        int t0 = tt * 64 + w * 16;
        int e0 = et * 192;

#pragma unroll
        for (int i = 0; i < 6; ++i) {
            int f4  = tid + i * 256;
            int row = f4 / 48, c4 = f4 % 48;
            float4v v = *(const float4v*)&proj[(size_t)b * Kc * Dc + (size_t)row * Dc + e0 + c4 * 4];
#pragma unroll
            for (int q = 0; q < 4; ++q) pt[row * 193 + c4 * 4 + q] = v[q];
        }

        const float* apx = sb + ((size_t)b * Tc + t0 + col) * Kc + quad * 8;
        short8 ah, al;
        split8(apx, ah, al);

        __syncthreads();

        float4v acc[12];
#pragma unroll
        for (int ni = 0; ni < 12; ++ni) acc[ni] = (float4v){0.f, 0.f, 0.f, 0.f};

#pragma unroll
        for (int ni = 0; ni < 12; ++ni) {
            float bv[8];
#pragma unroll
            for (int jj = 0; jj < 8; ++jj)
                bv[jj] = pt[(quad * 8 + jj) * 193 + ni * 16 + col];
            short8 bh, bl;
            split8(bv, bh, bl);
            acc[ni] = __builtin_amdgcn_mfma_f32_16x16x32_bf16(ah, bh, acc[ni], 0, 0, 0);
            acc[ni] = __builtin_amdgcn_mfma_f32_16x16x32_bf16(al, bh, acc[ni], 0, 0, 0);
            acc[ni] = __builtin_amdgcn_mfma_f32_16x16x32_bf16(ah, bl, acc[ni], 0, 0, 0);
        }

        float* op = out + ((size_t)b * Tc + t0 + quad * 4) * Dc + e0 + col;
#pragma unroll
        for (int ni = 0; ni < 12; ++ni)
#pragma unroll
            for (int r = 0; r < 4; ++r)
                op[(size_t)r * Dc + ni * 16] = acc[ni][r];
    }
}

extern "C" void kernel_launch(void* const* d_in, const int* in_sizes, int n_in,
                              void* d_out, int out_size, void* d_ws, size_t ws_size,
                              hipStream_t stream) {
    const float* x     = (const float*)d_in[0];
    const float* sb    = (const float*)d_in[1];
    const float* wqkv  = (const float*)d_in[2];
    const float* wout  = (const float*)d_in[3];
    const float* sfilt = (const float*)d_in[4];
    float* out = (float*)d_out;

    // workspace layout (~26.8 MB + 80 KB barrier slots)
    float* pb    = (float*)d_ws;                        // 16*XS_F f (12.6 MB)
    short* w_hi  = (short*)(pb + (size_t)16 * XS_F);    // WALL_F sh
    short* w_lo  = w_hi + (size_t)WALL_F;               // WALL_F sh
    short* xs_hi = w_lo + (size_t)WALL_F;               // XS_F sh
    short* xs_lo = xs_hi + (size_t)XS_F;                // XS_F sh
    float* c1    = (float*)(xs_lo + (size_t)XS_F);      // 589,824 f
    float* fhn   = c1 + (size_t)Bc * Kc * TD3;          // 3,072 f
    float* proj  = fhn + (size_t)Bc * Hc * Kc;          // XS_F f
    unsigned* bar = (unsigned*)((char*)d_ws + (size_t)28 * 1024 * 1024);

    hipMemsetAsync(bar, 0, 5 * BAR_STRIDE * sizeof(unsigned), stream);  // zero all barrier slots
    hipLaunchKernelGGL(mega, dim3(NBLK), dim3(256), 0, stream,
                       x, sb, wqkv, wout, sfilt, out,
                       pb, w_hi, w_lo, xs_hi, xs_lo, c1, fhn, proj, bar);
}

// Round 9
// 267.200 us; speedup vs baseline: 5.1960x; 3.1684x over previous
//
#include <hip/hip_runtime.h>

#define Bc 8
#define Tc 4096
#define Dc 768
#define Hc 12
#define HDc 64
#define Kc 32
#define TD3 2304
#define WQKV_F (TD3 * Dc)          // 1,769,472 floats
#define WALL_F ((TD3 + Dc) * Dc)   // 2,359,296 floats (wqkv + wout)
#define XS_F (Bc * Kc * Dc)        //   196,608 floats

typedef __attribute__((ext_vector_type(8))) short short8;
typedef __attribute__((ext_vector_type(4))) short short4v;
typedef __attribute__((ext_vector_type(4))) float float4v;

__device__ __forceinline__ float bf2f(unsigned short u) {
    unsigned v = ((unsigned)u) << 16;
    return __builtin_bit_cast(float, v);
}
__device__ __forceinline__ unsigned short f2bf(float f) {
    unsigned u = __builtin_bit_cast(unsigned, f);
    u += 0x7FFFu + ((u >> 16) & 1u);   // RNE
    return (unsigned short)(u >> 16);
}
__device__ __forceinline__ void split8(const float* p, short8& hi, short8& lo) {
#pragma unroll
    for (int i = 0; i < 8; ++i) {
        unsigned short h = f2bf(p[i]);
        hi[i] = (short)h;
        lo[i] = (short)f2bf(p[i] - bf2f(h));
    }
}
__device__ __forceinline__ void split4(const float4v v, short4v& h, short4v& l) {
#pragma unroll
    for (int q = 0; q < 4; ++q) {
        unsigned short hb = f2bf(v[q]);
        h[q] = (short)hb;
        l[q] = (short)f2bf(v[q] - bf2f(hb));
    }
}

// ---------------------------------------------------------------------------
// L1 (fused): bids [0,512) = k1 spectral GEMM; bids [512,2816) = weight
// fp32 -> bf16 hi/lo plane conversion co-tenants. (validated R5, unchanged)
// ---------------------------------------------------------------------------
__global__ __launch_bounds__(256) void k1_fused(const float* __restrict__ x,
                                                const float* __restrict__ sb,
                                                const float* __restrict__ wqkv,
                                                const float* __restrict__ wout,
                                                float* __restrict__ pb,
                                                short* __restrict__ w_hi,
                                                short* __restrict__ w_lo) {
    __shared__ float xt[32 * 193];
    __shared__ float st[32 * 33];

    int tid = threadIdx.x;
    int bid = blockIdx.x;

    if (bid >= 512) {                  // ---- weight conversion half
        int i = ((bid - 512) * 256 + tid) * 4;
        const float* src = (i < WQKV_F) ? (wqkv + i) : (wout + (i - WQKV_F));
        float4v v = *(const float4v*)src;
        short4v h, l;
        split4(v, h, l);
        *(short4v*)(w_hi + i) = h;
        *(short4v*)(w_lo + i) = l;
        return;
    }

    // ---- k1 half (R1-exact)
    int w    = tid >> 6;
    int lane = tid & 63;
    int col  = lane & 15;
    int quad = lane >> 4;

    int b  = bid >> 6;
    int dt = (bid >> 4) & 3;
    int tc = bid & 15;
    int d0 = dt * 192;
    size_t bT = (size_t)b * Tc + (size_t)tc * 256;

    float4v acc[2][3];
#pragma unroll
    for (int mi = 0; mi < 2; ++mi)
#pragma unroll
        for (int ni = 0; ni < 3; ++ni) acc[mi][ni] = (float4v){0.f, 0.f, 0.f, 0.f};

    for (int ks = 0; ks < 8; ++ks) {
        __syncthreads();
#pragma unroll
        for (int i = 0; i < 6; ++i) {
            int f4  = tid + i * 256;
            int row = f4 / 48, c4 = f4 % 48;
            float4v v = *(const float4v*)&x[(bT + ks * 32 + row) * Dc + d0 + c4 * 4];
#pragma unroll
            for (int q = 0; q < 4; ++q) xt[row * 193 + c4 * 4 + q] = v[q];
        }
        {
            int row = tid >> 3, c4 = tid & 7;
            float4v v = *(const float4v*)&sb[(bT + ks * 32 + row) * Kc + c4 * 4];
#pragma unroll
            for (int q = 0; q < 4; ++q) st[row * 33 + c4 * 4 + q] = v[q];
        }
        __syncthreads();

        short8 ah[2], al[2];
#pragma unroll
        for (int mi = 0; mi < 2; ++mi) {
            float av[8];
#pragma unroll
            for (int j = 0; j < 8; ++j)
                av[j] = st[(quad * 8 + j) * 33 + mi * 16 + col];
            split8(av, ah[mi], al[mi]);
        }
#pragma unroll
        for (int ni = 0; ni < 3; ++ni) {
            int nc = (w * 3 + ni) * 16 + col;
            float bv[8];
#pragma unroll
            for (int j = 0; j < 8; ++j)
                bv[j] = xt[(quad * 8 + j) * 193 + nc];
            short8 bh, bl;
            split8(bv, bh, bl);
#pragma unroll
            for (int mi = 0; mi < 2; ++mi) {
                acc[mi][ni] = __builtin_amdgcn_mfma_f32_16x16x32_bf16(ah[mi], bh, acc[mi][ni], 0, 0, 0);
                acc[mi][ni] = __builtin_amdgcn_mfma_f32_16x16x32_bf16(al[mi], bh, acc[mi][ni], 0, 0, 0);
                acc[mi][ni] = __builtin_amdgcn_mfma_f32_16x16x32_bf16(ah[mi], bl, acc[mi][ni], 0, 0, 0);
            }
        }
    }

    float* pbp = pb + (size_t)tc * XS_F;
#pragma unroll
    for (int mi = 0; mi < 2; ++mi)
#pragma unroll
        for (int ni = 0; ni < 3; ++ni)
#pragma unroll
            for (int r = 0; r < 4; ++r) {
                int kk = mi * 16 + quad * 4 + r;
                int dd = d0 + (w * 3 + ni) * 16 + col;
                pbp[((size_t)(b * Kc + kk)) * Dc + dd] = acc[mi][ni][r];
            }
}

// reduce 16 partials -> xs bf16 hi/lo planes (validated, unchanged)
__global__ __launch_bounds__(256) void k1r_reduce(const float* __restrict__ pb,
                                                  short* __restrict__ xs_hi,
                                                  short* __restrict__ xs_lo) {
    int i = (blockIdx.x * 256 + threadIdx.x) * 4;
    float4v s = (float4v){0.f, 0.f, 0.f, 0.f};
#pragma unroll
    for (int p = 0; p < 16; ++p) {
        float4v v = *(const float4v*)(pb + (size_t)p * XS_F + i);
#pragma unroll
        for (int q = 0; q < 4; ++q) s[q] += v[q];
    }
    short4v h, l;
    split4(s, h, l);
    *(short4v*)(xs_hi + i) = h;
    *(short4v*)(xs_lo + i) = l;
}

// K2: pure-plane GEMM (validated, unchanged: grid 288, wave tile 32x16)
__global__ __launch_bounds__(256) void k2_qkv(const short* __restrict__ xs_hi,
                                              const short* __restrict__ xs_lo,
                                              const short* __restrict__ w_hi,
                                              const short* __restrict__ w_lo,
                                              float* __restrict__ c1) {
    int lane = threadIdx.x & 63;
    int w    = threadIdx.x >> 6;
    int m    = lane & 15, quad = lane >> 4;
    int mb = blockIdx.x & 7;
    int nb = blockIdx.x >> 3;
    int m0 = mb * 32;
    int n0 = nb * 64 + w * 16;

    const short* a0h = xs_hi + (size_t)(m0 + m) * Dc + quad * 8;
    const short* a0l = xs_lo + (size_t)(m0 + m) * Dc + quad * 8;
    const short* a1h = a0h + (size_t)16 * Dc;
    const short* a1l = a0l + (size_t)16 * Dc;
    const short* bhp = w_hi + (size_t)(n0 + m) * Dc + quad * 8;
    const short* blp = w_lo + (size_t)(n0 + m) * Dc + quad * 8;

    float4v acc0 = (float4v){0.f, 0.f, 0.f, 0.f};
    float4v acc1 = (float4v){0.f, 0.f, 0.f, 0.f};
#pragma unroll 4
    for (int s = 0; s < 24; ++s) {
        short8 bh = *(const short8*)(bhp + s * 32);
        short8 bl = *(const short8*)(blp + s * 32);
        short8 h0 = *(const short8*)(a0h + s * 32);
        short8 l0 = *(const short8*)(a0l + s * 32);
        short8 h1 = *(const short8*)(a1h + s * 32);
        short8 l1 = *(const short8*)(a1l + s * 32);
        acc0 = __builtin_amdgcn_mfma_f32_16x16x32_bf16(h0, bh, acc0, 0, 0, 0);
        acc0 = __builtin_amdgcn_mfma_f32_16x16x32_bf16(l0, bh, acc0, 0, 0, 0);
        acc0 = __builtin_amdgcn_mfma_f32_16x16x32_bf16(h0, bl, acc0, 0, 0, 0);
        acc1 = __builtin_amdgcn_mfma_f32_16x16x32_bf16(h1, bh, acc1, 0, 0, 0);
        acc1 = __builtin_amdgcn_mfma_f32_16x16x32_bf16(l1, bh, acc1, 0, 0, 0);
        acc1 = __builtin_amdgcn_mfma_f32_16x16x32_bf16(h1, bl, acc1, 0, 0, 0);
    }
    float* cp0 = c1 + (size_t)(m0 + quad * 4) * TD3 + n0 + m;
    float* cp1 = cp0 + (size_t)16 * TD3;
#pragma unroll
    for (int r = 0; r < 4; ++r) {
        cp0[(size_t)r * TD3] = acc0[r];
        cp1[(size_t)r * TD3] = acc1[r];
    }
}

// ---------------------------------------------------------------------------
// K4 (+FHN): per block, stage fhn for its 64 rows x 12 heads into LDS
// (replaces the separate k3 launch; c1 is L2-resident so the 768 extra
// dot-products cost ~2-3us aggregate), then R5's validated plane GEMM
// proj[r,e] = sum_c (fhn*v_spec)[r,c] * wout[e,c] with fp32 proj epilogue
// (R5 form — NOT R6's pT planes, which correlated with both regressions).
// Grid 192; block covers rows r0..r0+63 (r0 = 64*(bid&3)); row_l = w*16+m.
// ---------------------------------------------------------------------------
__global__ __launch_bounds__(256) void k4_proj(const float* __restrict__ c1,
                                               const float* __restrict__ sfilt,
                                               const short* __restrict__ wo_hi,
                                               const short* __restrict__ wo_lo,
                                               float* __restrict__ proj) {
    __shared__ float fh[64][13];       // +1 pad
    int tid = threadIdx.x;
    int r0  = 64 * (blockIdx.x & 3);

    // FHN stage: 768 (row,h) pairs, 3 per thread
    for (int u = tid; u < 768; u += 256) {
        int h = u >> 6, row_l = u & 63;
        int r = r0 + row_l;
        int kk = r & 31;
        const float* qp = c1 + (size_t)r * TD3 + h * HDc;
        const float* kp = qp + Dc;
        float s = 0.f;
#pragma unroll
        for (int dd = 0; dd < HDc; dd += 4) {
            float4v qv = *(const float4v*)(qp + dd);
            float4v kv = *(const float4v*)(kp + dd);
#pragma unroll
            for (int q2 = 0; q2 < 4; ++q2) s = fmaf(qv[q2], kv[q2], s);
        }
        s *= 0.125f;
        float filt = 1.f / (1.f + __expf(-sfilt[h * 32 + kk]));
        s *= filt;
        float as    = fabsf(s);
        float scale = fmaxf(as, 1e-6f);
        float sn    = s / scale;
        float gate  = 1.f / (1.f + __expf(-(as - 0.5f) * 10.f));
        float I     = sn * (0.1f + 0.9f * gate);
        const float alpha = 0.08f;
        const float denom = 1.064f;
        float v = 0.f, w = 0.f;
#pragma unroll
        for (int it = 0; it < 2; ++it) {
            float dv = v - (v * v * v) / 3.f - w + I;
            float vn = v + dv;
            float wn = (w + (vn + 0.7f) * alpha) / denom;
            v = fminf(fmaxf(vn, -3.f), 3.f);
            w = fminf(fmaxf(wn, -3.f), 3.f);
        }
        fh[row_l][h] = v * scale;
    }
    __syncthreads();

    int w    = tid >> 6;
    int lane = tid & 63;
    int wave = blockIdx.x * 4 + w;
    int mb = wave & 15;
    int nt = wave >> 4;
    int m0 = mb * 16, n0 = nt * 16;
    int m = lane & 15, quad = lane >> 4;
    int row_l = w * 16 + m;            // = m0 + m - r0

    const short* bhp = wo_hi + (size_t)(n0 + m) * Dc + quad * 8;
    const short* blp = wo_lo + (size_t)(n0 + m) * Dc + quad * 8;

    int r = m0 + m;
    const float* apx = c1 + (size_t)r * TD3 + 2 * Dc + quad * 8;

    float4v acc = (float4v){0.f, 0.f, 0.f, 0.f};
#pragma unroll 4
    for (int s = 0; s < 24; ++s) {
        int h = (s * 32 + quad * 8) >> 6;
        float f = fh[row_l][h];
        float av[8];
#pragma unroll
        for (int i = 0; i < 8; ++i) av[i] = apx[s * 32 + i] * f;
        short8 ah, al;
        split8(av, ah, al);
        short8 bh = *(const short8*)(bhp + s * 32);
        short8 bl = *(const short8*)(blp + s * 32);
        acc = __builtin_amdgcn_mfma_f32_16x16x32_bf16(ah, bh, acc, 0, 0, 0);
        acc = __builtin_amdgcn_mfma_f32_16x16x32_bf16(al, bh, acc, 0, 0, 0);
        acc = __builtin_amdgcn_mfma_f32_16x16x32_bf16(ah, bl, acc, 0, 0, 0);
    }
    float* cp = proj + (size_t)(m0 + quad * 4) * Dc + n0 + m;
#pragma unroll
    for (int rr = 0; rr < 4; ++rr) cp[(size_t)rr * Dc] = acc[rr];
}

// K5: out GEMM (R5-exact: LDS proj tile, raw fp32 sb, grid 2048)
__global__ __launch_bounds__(256) void k5_out(const float* __restrict__ proj,
                                              const float* __restrict__ sb,
                                              float* __restrict__ out) {
    __shared__ float pt[32 * 193];

    int tid  = threadIdx.x;
    int w    = tid >> 6;
    int lane = tid & 63;
    int col  = lane & 15;
    int quad = lane >> 4;

    int bid = blockIdx.x;
    int b  = bid >> 8;
    int tt = (bid >> 2) & 63;
    int et = bid & 3;
    int t0 = tt * 64 + w * 16;
    int e0 = et * 192;

#pragma unroll
    for (int i = 0; i < 6; ++i) {
        int f4  = tid + i * 256;
        int row = f4 / 48, c4 = f4 % 48;
        float4v v = *(const float4v*)&proj[(size_t)b * Kc * Dc + (size_t)row * Dc + e0 + c4 * 4];
#pragma unroll
        for (int q = 0; q < 4; ++q) pt[row * 193 + c4 * 4 + q] = v[q];
    }

    const float* apx = sb + ((size_t)b * Tc + t0 + col) * Kc + quad * 8;
    short8 ah, al;
    split8(apx, ah, al);

    __syncthreads();

    float4v acc[12];
#pragma unroll
    for (int ni = 0; ni < 12; ++ni) acc[ni] = (float4v){0.f, 0.f, 0.f, 0.f};

#pragma unroll
    for (int ni = 0; ni < 12; ++ni) {
        float bv[8];
#pragma unroll
        for (int j = 0; j < 8; ++j)
            bv[j] = pt[(quad * 8 + j) * 193 + ni * 16 + col];
        short8 bh, bl;
        split8(bv, bh, bl);
        acc[ni] = __builtin_amdgcn_mfma_f32_16x16x32_bf16(ah, bh, acc[ni], 0, 0, 0);
        acc[ni] = __builtin_amdgcn_mfma_f32_16x16x32_bf16(al, bh, acc[ni], 0, 0, 0);
        acc[ni] = __builtin_amdgcn_mfma_f32_16x16x32_bf16(ah, bl, acc[ni], 0, 0, 0);
    }

    float* op = out + ((size_t)b * Tc + t0 + quad * 4) * Dc + e0 + col;
#pragma unroll
    for (int ni = 0; ni < 12; ++ni)
#pragma unroll
        for (int r = 0; r < 4; ++r)
            op[(size_t)r * Dc + ni * 16] = acc[ni][r];
}

extern "C" void kernel_launch(void* const* d_in, const int* in_sizes, int n_in,
                              void* d_out, int out_size, void* d_ws, size_t ws_size,
                              hipStream_t stream) {
    const float* x     = (const float*)d_in[0];
    const float* sb    = (const float*)d_in[1];
    const float* wqkv  = (const float*)d_in[2];
    const float* wout  = (const float*)d_in[3];
    const float* sfilt = (const float*)d_in[4];
    float* out = (float*)d_out;

    // workspace layout (R5-identical, ~26.7 MB; fhn slot retained but unused)
    float* pb    = (float*)d_ws;                        // 16*XS_F f (12.6 MB)
    short* w_hi  = (short*)(pb + (size_t)16 * XS_F);    // WALL_F sh
    short* w_lo  = w_hi + (size_t)WALL_F;               // WALL_F sh
    short* xs_hi = w_lo + (size_t)WALL_F;               // XS_F sh
    short* xs_lo = xs_hi + (size_t)XS_F;                // XS_F sh
    float* c1    = (float*)(xs_lo + (size_t)XS_F);      // 589,824 f
    float* fhn   = c1 + (size_t)Bc * Kc * TD3;          // (unused hole)
    float* proj  = fhn + (size_t)Bc * Hc * Kc;          // XS_F f

    const short* wo_hi = w_hi + (size_t)WQKV_F;
    const short* wo_lo = w_lo + (size_t)WQKV_F;

    hipLaunchKernelGGL(k1_fused,   dim3(2816), dim3(256), 0, stream,
                       x, sb, wqkv, wout, pb, w_hi, w_lo);
    hipLaunchKernelGGL(k1r_reduce, dim3(192),  dim3(256), 0, stream, pb, xs_hi, xs_lo);
    hipLaunchKernelGGL(k2_qkv,     dim3(288),  dim3(256), 0, stream, xs_hi, xs_lo, w_hi, w_lo, c1);
    hipLaunchKernelGGL(k4_proj,    dim3(192),  dim3(256), 0, stream, c1, sfilt, wo_hi, wo_lo, proj);
    hipLaunchKernelGGL(k5_out,     dim3(2048), dim3(256), 0, stream, proj, sb, out);
}